// Round 4
// baseline (1261.487 us; speedup 1.0000x reference)
//
#include <hip/hip_runtime.h>
#include <hip/hip_bf16.h>
#include <math.h>

// Problem constants
#define B_ 8
#define Q_ 200
#define K_ 16384
#define D_ 256
#define H_ 8
#define DH_ 32
#define ALIGNK_ 96
#define CROSSK_ 1024
#define FF_ 1024
#define BQ_ (B_*Q_)     // 1600
#define BK_ (B_*K_)     // 131072

typedef unsigned short u16;
typedef short bf16x8 __attribute__((ext_vector_type(8)));
typedef float f32x4 __attribute__((ext_vector_type(4)));

__device__ __forceinline__ float b2f(u16 u){ return __uint_as_float(((unsigned)u)<<16); }
__device__ __forceinline__ u16 f2b(float f){
  unsigned x = __float_as_uint(f);
  unsigned r = x + 0x7FFFu + ((x>>16)&1u);   // round-to-nearest-even
  return (u16)(r>>16);
}
__device__ __forceinline__ unsigned p2u(float lo, float hi){
  return (unsigned)f2b(lo) | ((unsigned)f2b(hi)<<16);
}
__device__ __forceinline__ uint4 pk8(float4 a, float4 b){
  return make_uint4(p2u(a.x,a.y), p2u(a.z,a.w), p2u(b.x,b.y), p2u(b.z,b.w));
}
// order-preserving float->uint key (larger float => larger key)
__device__ __forceinline__ unsigned fkey(float f){ unsigned b=__float_as_uint(f); return (b&0x80000000u)? ~b : (b|0x80000000u); }
__device__ __forceinline__ float funkey(unsigned k){ unsigned b=(k&0x80000000u)? (k^0x80000000u) : ~k; return __uint_as_float(b); }
__device__ __forceinline__ float gelu_f(float x){ return 0.5f*x*(1.0f+erff(x*0.70710678118654752f)); }
__device__ __forceinline__ float sigmoid_f(float x){ return 1.0f/(1.0f+__expf(-x)); }

// ---------------------------------------------------------------------------
// General NT GEMM:  C[m,n] = sum_k A[m,k]*B[n,k]  (fp32 acc). A/B each either
// fp32 (converted to bf16 in registers) or bf16. Tile 64x64, BK=64, 4 waves.
// Modes: optional fp32 bias[n], act (1=gelu,2=sigmoid), out fp32 or bf16,
//        per-column atomic-max (importance), optional A-row gather.
// ---------------------------------------------------------------------------
struct GArgs {
  const void* A; const void* B; const float* bias;
  float* Cf; u16* Cb; unsigned* amax;
  const int* gather;
  long lda, ldb, ldc;
  long sA, sB, sC, sAmax, sGather;
  int M, N, K, act;
};

template<int AF32, int BF32>
__global__ __launch_bounds__(256) void gemm_bt(GArgs g)
{
  const int tid = threadIdx.x;
  const int bz = blockIdx.z;
  const int m0 = blockIdx.y*64, n0 = blockIdx.x*64;
  const int lane = tid & 63, wave = tid >> 6;
  const int wr = wave >> 1, wc = wave & 1;
  __shared__ __align__(16) u16 As[64][72];
  __shared__ __align__(16) u16 Bs[64][72];
  f32x4 acc[2][2] = {};

  const int lrow = tid>>2;
  const int lk = (tid&3)*16;
  int ar = m0 + lrow; if (ar > g.M-1) ar = g.M-1;
  if (g.gather) ar = g.gather[(long)bz*g.sGather + ar];
  int br = n0 + lrow; if (br > g.N-1) br = g.N-1;
  long aoff = (long)bz*g.sA + (long)ar*g.lda + lk;
  long boff = (long)bz*g.sB + (long)br*g.ldb + lk;

  const int nk = g.K >> 6;
  for (int kt=0; kt<nk; ++kt){
    uint4 wa0, wa1, wb0, wb1;
    if (AF32){
      const float* p = (const float*)g.A + aoff;
      float4 f0 = *(const float4*)(p+0);
      float4 f1 = *(const float4*)(p+4);
      float4 f2v= *(const float4*)(p+8);
      float4 f3 = *(const float4*)(p+12);
      wa0 = pk8(f0,f1); wa1 = pk8(f2v,f3);
    } else {
      const u16* p = (const u16*)g.A + aoff;
      wa0 = *(const uint4*)p; wa1 = *(const uint4*)(p+8);
    }
    if (BF32){
      const float* p = (const float*)g.B + boff;
      float4 f0 = *(const float4*)(p+0);
      float4 f1 = *(const float4*)(p+4);
      float4 f2v= *(const float4*)(p+8);
      float4 f3 = *(const float4*)(p+12);
      wb0 = pk8(f0,f1); wb1 = pk8(f2v,f3);
    } else {
      const u16* p = (const u16*)g.B + boff;
      wb0 = *(const uint4*)p; wb1 = *(const uint4*)(p+8);
    }
    aoff += 64; boff += 64;
    __syncthreads();
    *(uint4*)&As[lrow][lk]   = wa0; *(uint4*)&As[lrow][lk+8] = wa1;
    *(uint4*)&Bs[lrow][lk]   = wb0; *(uint4*)&Bs[lrow][lk+8] = wb1;
    __syncthreads();
    #pragma unroll
    for (int kk=0; kk<2; ++kk){
      const int ko = kk*32 + (lane>>4)*8;
      bf16x8 af0 = *(const bf16x8*)&As[wr*32      + (lane&15)][ko];
      bf16x8 af1 = *(const bf16x8*)&As[wr*32 + 16 + (lane&15)][ko];
      bf16x8 bf0 = *(const bf16x8*)&Bs[wc*32      + (lane&15)][ko];
      bf16x8 bf1 = *(const bf16x8*)&Bs[wc*32 + 16 + (lane&15)][ko];
      acc[0][0] = __builtin_amdgcn_mfma_f32_16x16x32_bf16(af0, bf0, acc[0][0], 0,0,0);
      acc[0][1] = __builtin_amdgcn_mfma_f32_16x16x32_bf16(af0, bf1, acc[0][1], 0,0,0);
      acc[1][0] = __builtin_amdgcn_mfma_f32_16x16x32_bf16(af1, bf0, acc[1][0], 0,0,0);
      acc[1][1] = __builtin_amdgcn_mfma_f32_16x16x32_bf16(af1, bf1, acc[1][1], 0,0,0);
    }
  }

  if (g.amax){
    // per-column max over rows (M-clamp duplicates a valid row -> max unaffected)
    #pragma unroll
    for (int j=0;j<2;j++){
      float mx = -3.0e38f;
      #pragma unroll
      for (int i=0;i<2;i++)
        #pragma unroll
        for (int r=0;r<4;r++) mx = fmaxf(mx, acc[i][j][r]);
      mx = fmaxf(mx, __shfl_xor(mx, 16));
      mx = fmaxf(mx, __shfl_xor(mx, 32));
      if ((lane>>4)==0){
        int n = n0 + wc*32 + j*16 + (lane&15);
        if (n < g.N) atomicMax(&g.amax[(long)bz*g.sAmax + n], fkey(mx));
      }
    }
    return;
  }

  #pragma unroll
  for (int i=0;i<2;i++)
  #pragma unroll
  for (int j=0;j<2;j++)
  #pragma unroll
  for (int r=0;r<4;r++){
    int m = m0 + wr*32 + i*16 + (lane>>4)*4 + r;   // C row = quad*4+reg
    int n = n0 + wc*32 + j*16 + (lane&15);          // C col = lane&15
    if (m < g.M && n < g.N){
      float v = acc[i][j][r];
      if (g.bias) v += g.bias[n];
      if (g.act==1) v = gelu_f(v);
      else if (g.act==2) v = sigmoid_f(v);
      long ci = (long)bz*g.sC + (long)m*g.ldc + n;
      if (g.Cf) g.Cf[ci] = v; else g.Cb[ci] = f2b(v);
    }
  }
}

// ---------------------------------------------------------------------------
// In-place row l2-normalize (D=256, bf16), x /= max(||x||,1e-6). 4 rows/block.
// ---------------------------------------------------------------------------
__global__ __launch_bounds__(256) void l2norm_rows(u16* x, int rows)
{
  int row = blockIdx.x*4 + (threadIdx.x>>6);
  int lane = threadIdx.x & 63;
  if (row >= rows) return;
  u16* p = x + (long)row*256;
  float v[4]; float s = 0.f;
  #pragma unroll
  for (int i=0;i<4;i++){ v[i] = b2f(p[lane + i*64]); s += v[i]*v[i]; }
  #pragma unroll
  for (int off=32; off; off>>=1) s += __shfl_xor(s, off);
  float inv = 1.0f / fmaxf(sqrtf(s), 1e-6f);
  #pragma unroll
  for (int i=0;i<4;i++) p[lane + i*64] = f2b(v[i]*inv);
}

// ---------------------------------------------------------------------------
// Exact top-RANK of a 16384-long row. Bitwise rank-select on order-preserving
// keys + index tie-break (smallest indices first) == jax.lax.top_k's set.
// ---------------------------------------------------------------------------
__global__ __launch_bounds__(256) void topk_kernel(const float* inF, const unsigned* inK,
    long in_stride, int RANK, float* out_val, int* out_idx)
{
  __shared__ int red[4];
  __shared__ int poss;
  int row = blockIdx.x, tid = threadIdx.x;
  unsigned kr[64];
  if (inF){
    const float* p = inF + (long)row*in_stride;
    #pragma unroll
    for (int j=0;j<64;j++) kr[j] = fkey(p[tid + j*256]);
  } else {
    const unsigned* p = inK + (long)row*in_stride;
    #pragma unroll
    for (int j=0;j<64;j++) kr[j] = p[tid + j*256];
  }
  if (tid==0) poss = 0;

  unsigned u = 0;
  for (int bit=31; bit>=0; --bit){
    unsigned cand = u | (1u<<bit);
    int c = 0;
    #pragma unroll
    for (int j=0;j<64;j++) c += (kr[j] >= cand) ? 1 : 0;
    for (int off=32; off; off>>=1) c += __shfl_down(c, off);
    __syncthreads();
    if ((tid&63)==0) red[tid>>6] = c;
    __syncthreads();
    c = red[0]+red[1]+red[2]+red[3];
    if (c >= RANK) u = cand;
  }
  int cgt = 0;
  #pragma unroll
  for (int j=0;j<64;j++) cgt += (kr[j] > u) ? 1 : 0;
  for (int off=32; off; off>>=1) cgt += __shfl_down(cgt, off);
  __syncthreads();
  if ((tid&63)==0) red[tid>>6] = cgt;
  __syncthreads();
  cgt = red[0]+red[1]+red[2]+red[3];
  int Req = RANK - cgt;   // >=1 always
  int t = 0;
  for (int bit=13; bit>=0; --bit){
    int cand = t | (1<<bit);
    int c = 0;
    #pragma unroll
    for (int j=0;j<64;j++) c += (kr[j]==u && (tid + j*256) < cand) ? 1 : 0;
    for (int off=32; off; off>>=1) c += __shfl_down(c, off);
    __syncthreads();
    if ((tid&63)==0) red[tid>>6] = c;
    __syncthreads();
    c = red[0]+red[1]+red[2]+red[3];
    if (c < Req) t = cand;
  }
  __syncthreads();
  #pragma unroll
  for (int j=0;j<64;j++){
    int e = tid + j*256;
    unsigned kk = kr[j];
    if (kk > u || (kk == u && e <= t)){
      int p2 = atomicAdd(&poss, 1);
      out_val[(long)row*RANK + p2] = funkey(kk);
      out_idx[(long)row*RANK + p2] = e;
    }
  }
}

// ---------------------------------------------------------------------------
// aligned[row,:] = softmax(vals96) . memory[b, idx96, :]   (memory fp32)
// ---------------------------------------------------------------------------
__global__ __launch_bounds__(256) void align_combine(const float* vals, const int* idx,
    const float* memory, float* alignedv)
{
  __shared__ float w[96];
  __shared__ int id[96];
  __shared__ float reds[2];
  int row = blockIdx.x, tid = threadIdx.x;
  int b = row / 200;
  if (tid < 96){ w[tid] = vals[(long)row*96 + tid]; id[tid] = idx[(long)row*96 + tid]; }
  __syncthreads();
  if (tid < 64){
    float a = w[tid];
    float bb2 = (tid < 32) ? w[64+tid] : -3e38f;
    float m = fmaxf(a, bb2);
    #pragma unroll
    for (int off=32; off; off>>=1) m = fmaxf(m, __shfl_xor(m, off));
    if (tid==0) reds[0] = m;
  }
  __syncthreads();
  float m = reds[0];
  if (tid < 96) w[tid] = __expf(w[tid]-m);
  __syncthreads();
  if (tid < 64){
    float a = w[tid] + ((tid<32)? w[64+tid] : 0.f);
    #pragma unroll
    for (int off=32; off; off>>=1) a += __shfl_xor(a, off);
    if (tid==0) reds[1] = a;
  }
  __syncthreads();
  float invs = 1.0f/reds[1];
  float acc = 0.f;
  const float* mb = memory + (long)b*K_*D_;
  for (int k=0;k<96;k++) acc += w[k] * mb[(long)id[k]*D_ + tid];
  alignedv[(long)row*256 + tid] = acc*invs;
}

__global__ void make_cat(const float* q, const float* alignedv, u16* cat)
{
  int row = blockIdx.x, tid = threadIdx.x;
  long i = (long)row*256 + tid;
  cat[(long)row*512 + tid]       = f2b(q[i]);
  cat[(long)row*512 + 256 + tid] = f2b(alignedv[i]);
}

__global__ void combine_gate(const float* q, const float* q_pos, const float* alignedv,
    const float* gate, float* qx, u16* qx_b, u16* qk_b)
{
  int row = blockIdx.x, tid = threadIdx.x;
  long i = (long)row*256 + tid;
  float v = q[i] + gate[i]*alignedv[i];
  qx[i] = v;
  qx_b[i] = f2b(v);
  qk_b[i] = f2b(v + q_pos[i]);
}

// ---------------------------------------------------------------------------
// t = x + y; LN over D=256 (biased var, eps 1e-5). Optional outputs.
// fminf/fmaxf launder NaN (return the non-NaN operand) -> finite diagnostics.
// ---------------------------------------------------------------------------
__global__ __launch_bounds__(256) void add_ln(const float* x, const float* y,
    const float* g, const float* bb, const float* q_pos,
    float* out_f, u16* out_b, u16* out_pos_b)
{
  __shared__ float red[8];
  int row = blockIdx.x, tid = threadIdx.x;
  long i = (long)row*256 + tid;
  float t = fminf(fmaxf(x[i] + y[i], -1e6f), 1e6f);
  float s1 = t, s2 = t*t;
  #pragma unroll
  for (int off=32; off; off>>=1){ s1 += __shfl_down(s1,off); s2 += __shfl_down(s2,off); }
  if ((tid&63)==0){ red[(tid>>6)*2] = s1; red[(tid>>6)*2+1] = s2; }
  __syncthreads();
  s1 = red[0]+red[2]+red[4]+red[6];
  s2 = red[1]+red[3]+red[5]+red[7];
  float mu = s1 * (1.0f/256.0f);
  float var = fmaxf(s2 * (1.0f/256.0f) - mu*mu, 0.f);
  float rstd = rsqrtf(var + 1e-5f);
  float v = (t-mu)*rstd*g[tid] + bb[tid];
  if (out_f) out_f[i] = v;
  if (out_b) out_b[i] = f2b(v);
  if (out_pos_b) out_pos_b[i] = f2b(v + q_pos[i]);
}

__global__ void fill_u32(unsigned* p, unsigned val, int n)
{ int i = blockIdx.x*256 + threadIdx.x; if (i<n) p[i] = val; }

// ---------------------------------------------------------------------------
// Fused MHA (flash-style, online softmax). One block per (b, h, 64-q-tile).
// Q/K/V bf16 (staged buffers); bias (optional, cross) fp32 gathered via kidx.
// ---------------------------------------------------------------------------
__global__ __launch_bounds__(256) void attn_kernel(
    const u16* Qb, int q_stride,
    const u16* KVb, int kv_stride, int k_off, int v_off, int Lk,
    const float* bias, const int* kidx,
    u16* outp, float scale)
{
  __shared__ float Qs[64][36];
  __shared__ float Ks[64][36];
  __shared__ float Vs[64][36];
  __shared__ float Ps[64][65];
  __shared__ int kid_s[64];
  int b = blockIdx.z, h = blockIdx.y, q0 = blockIdx.x*64;
  int tid = threadIdx.x;
  int cg = tid & 3, r = tid >> 2;

  for (int e=tid; e<2048; e+=256){
    int row = e>>5, col = e&31;
    int qr = q0+row; if (qr > 199) qr = 199;
    Qs[row][col] = b2f(Qb[((long)(b*200+qr))*q_stride + h*32 + col]) * scale;
  }
  float o[8];
  #pragma unroll
  for (int i=0;i<8;i++) o[i]=0.f;
  float mrun = -3e38f, lrun = 0.f;
  __syncthreads();
  float qreg[32];
  #pragma unroll
  for (int d=0; d<32; d++) qreg[d] = Qs[r][d];
  int qglob = q0 + r; if (qglob>199) qglob=199;
  const long bias_row = ((long)(b*200 + qglob))*(long)K_;

  for (int j0=0; j0<Lk; j0+=64){
    if (kidx && tid<64) kid_s[tid] = kidx[b*CROSSK_ + j0 + tid];
    for (int e=tid; e<2048; e+=256){
      int row = e>>5, col = e&31;
      int kr = j0+row; if (kr > Lk-1) kr = Lk-1;
      long base = ((long)(b*Lk + kr))*kv_stride;
      Ks[row][col] = b2f(KVb[base + k_off + col]);
      Vs[row][col] = b2f(KVb[base + v_off + col]);
    }
    __syncthreads();
    float sv[16];
    float mloc = -3e38f;
    #pragma unroll
    for (int jj=0;jj<16;jj++){
      int c = cg + jj*4;
      float a = 0.f;
      #pragma unroll
      for (int d=0;d<32;d++) a += qreg[d]*Ks[c][d];
      if (kidx) a += bias[bias_row + kid_s[c]];
      if (j0 + c >= Lk) a = -3e38f;
      sv[jj] = a; mloc = fmaxf(mloc, a);
    }
    mloc = fmaxf(mloc, __shfl_xor(mloc,1));
    mloc = fmaxf(mloc, __shfl_xor(mloc,2));
    float mnew = fmaxf(mrun, mloc);
    float alpha = __expf(mrun - mnew);
    float lloc = 0.f;
    #pragma unroll
    for (int jj=0;jj<16;jj++){
      int c = cg + jj*4;
      float p = (j0 + c >= Lk) ? 0.f : __expf(sv[jj]-mnew);
      Ps[r][c] = p; lloc += p;
    }
    lloc += __shfl_xor(lloc,1);
    lloc += __shfl_xor(lloc,2);
    lrun = lrun*alpha + lloc;
    #pragma unroll
    for (int i=0;i<8;i++) o[i]*=alpha;
    __syncthreads();
    for (int c=0;c<64;c++){
      float p = Ps[r][c];
      #pragma unroll
      for (int i=0;i<8;i++) o[i] += p * Vs[c][cg*8+i];
    }
    mrun = mnew;
    __syncthreads();
  }
  if (q0 + r < 200){
    float invl = 1.0f/fmaxf(lrun, 1e-30f);
    #pragma unroll
    for (int i=0;i<8;i++)
      outp[((long)(b*200 + q0 + r))*256 + h*32 + cg*8 + i] = f2b(o[i]*invl);
  }
}

// ---------------------------------------------------------------------------
extern "C" void kernel_launch(void* const* d_in, const int* in_sizes, int n_in,
                              void* d_out, int out_size, void* d_ws, size_t ws_size,
                              hipStream_t stream)
{
  const float* q        = (const float*)d_in[0];
  const float* q_pos    = (const float*)d_in[1];
  const float* memory   = (const float*)d_in[2];
  const float* cbias    = (const float*)d_in[3];
  const float* align_wq = (const float*)d_in[4];
  const float* align_wm = (const float*)d_in[5];
  const float* gate_w1  = (const float*)d_in[6];
  const float* gate_b1  = (const float*)d_in[7];
  const float* gate_w2  = (const float*)d_in[8];
  const float* gate_b2  = (const float*)d_in[9];
  const float* cross_wq = (const float*)d_in[10];
  const float* cross_wm = (const float*)d_in[11];
  const float* sa_in_w  = (const float*)d_in[12];
  const float* sa_in_b  = (const float*)d_in[13];
  const float* sa_out_w = (const float*)d_in[14];
  const float* sa_out_b = (const float*)d_in[15];
  const float* ca_in_w  = (const float*)d_in[16];
  const float* ca_in_b  = (const float*)d_in[17];
  const float* ca_out_w = (const float*)d_in[18];
  const float* ca_out_b = (const float*)d_in[19];
  const float* ffn_w1   = (const float*)d_in[20];
  const float* ffn_b1   = (const float*)d_in[21];
  const float* ffn_w2   = (const float*)d_in[22];
  const float* ffn_b2   = (const float*)d_in[23];
  const float* n1_g = (const float*)d_in[24];
  const float* n1_b = (const float*)d_in[25];
  const float* n2_g = (const float*)d_in[26];
  const float* n2_b = (const float*)d_in[27];
  const float* n3_g = (const float*)d_in[28];
  const float* n3_b = (const float*)d_in[29];
  float* out = (float*)d_out;   // reference output dtype is fp32

  // ---- workspace layout, fitted to ws_size (deterministic per call) ----
  char* wsb = (char*)d_ws;
  size_t off = 0;
  auto alloc = [&](size_t bytes)->char*{
    char* p = wsb + off; off = (off + bytes + 255) & ~(size_t)255; return p;
  };
  // small fixed buffers (~22 MB)
  u16*    qn_bf   = (u16*)   alloc((size_t)BQ_*D_*2);
  float*  vals96  = (float*) alloc((size_t)BQ_*96*4);
  int*    idx96   = (int*)   alloc((size_t)BQ_*96*4);
  float*  alignedv= (float*) alloc((size_t)BQ_*D_*4);
  u16*    cat_bf  = (u16*)   alloc((size_t)BQ_*512*2);
  u16*    h_bf    = (u16*)   alloc((size_t)BQ_*D_*2);
  float*  gatebuf = (float*) alloc((size_t)BQ_*D_*4);
  float*  qx      = (float*) alloc((size_t)BQ_*D_*4);
  u16*    qx_bf   = (u16*)   alloc((size_t)BQ_*D_*2);
  u16*    qk_bf   = (u16*)   alloc((size_t)BQ_*D_*2);
  u16*    qpos2_bf= (u16*)   alloc((size_t)BQ_*D_*2);
  u16*    qkv_bf  = (u16*)   alloc((size_t)BQ_*768*2);
  u16*    attO_bf = (u16*)   alloc((size_t)BQ_*D_*2);
  float*  q2      = (float*) alloc((size_t)BQ_*D_*4);
  unsigned* imp   = (unsigned*)alloc((size_t)B_*K_*4);
  int*    kidx    = (int*)   alloc((size_t)B_*CROSSK_*4);
  u16*    cq_bf   = (u16*)   alloc((size_t)BQ_*D_*2);
  u16*    f1_bf   = (u16*)   alloc((size_t)BQ_*FF_*2);
  float*  f2buf   = (float*) alloc((size_t)BQ_*D_*4);

  // big buffers: mn (>= kvbuf size, kvbuf aliases it) and simbuf
  const size_t kv_bytes   = (size_t)B_*CROSSK_*512*2;        // 8.4 MB
  const size_t mn_full    = (size_t)BK_*D_*2;                // 67 MB
  const size_t mn_small   = (size_t)K_*D_*2;                 // 8.4 MB
  const size_t sim_full   = (size_t)BQ_*K_*4;                // 105 MB
  size_t remain = (ws_size > off) ? ws_size - off : 0;
  bool fullws = remain >= mn_full + sim_full + (1u<<20);
  size_t mn_bytes = fullws ? mn_full : (mn_small > kv_bytes ? mn_small : kv_bytes);
  int simRows;                      // rows of sim materialized at once
  if (fullws) simRows = BQ_;
  else {
    size_t left = (remain > mn_bytes + (1u<<18)) ? remain - mn_bytes - (1u<<18) : 0;
    long r = (long)(left / ((size_t)K_*4));
    simRows = (int)(r < 8 ? 8 : (r > Q_ ? Q_ : r));
  }
  u16*   mn_bf  = (u16*)  alloc(mn_bytes);
  u16*   kvbuf  = (u16*)  mn_bf;     // alias: mn dead before kvbuf is written
  float* simbuf = (float*)alloc((size_t)simRows*K_*4);

  auto gemm = [&](int af32, int bf32,
                  const void* A, long lda, long sA,
                  const void* Bm, long ldb, long sB,
                  int M, int N, int Kd,
                  const float* bias, int act,
                  float* Cf, u16* Cb, long ldc, long sC,
                  unsigned* amax, long sAmax,
                  const int* gather, long sGather, int Z){
    GArgs ga;
    ga.A=A; ga.B=Bm; ga.bias=bias; ga.Cf=Cf; ga.Cb=Cb; ga.amax=amax; ga.gather=gather;
    ga.lda=lda; ga.ldb=ldb; ga.ldc=ldc; ga.sA=sA; ga.sB=sB; ga.sC=sC;
    ga.sAmax=sAmax; ga.sGather=sGather;
    ga.M=M; ga.N=N; ga.K=Kd; ga.act=act;
    dim3 grid(N/64, (M+63)/64, Z);
    if (af32 && bf32)      gemm_bt<1,1><<<grid, 256, 0, stream>>>(ga);
    else if (af32)         gemm_bt<1,0><<<grid, 256, 0, stream>>>(ga);
    else if (bf32)         gemm_bt<0,1><<<grid, 256, 0, stream>>>(ga);
    else                   gemm_bt<0,0><<<grid, 256, 0, stream>>>(ga);
  };
  const float ascale = 0.17677669529663687f;  // 1/sqrt(32)

  // --- align: projections + l2norm + sim + top-96 ---
  gemm(1,1, q,256,0, align_wq,256,0, BQ_,256,256, nullptr,0, nullptr,qn_bf,256,0, nullptr,0, nullptr,0, 1);
  l2norm_rows<<<BQ_/4,256,0,stream>>>(qn_bf, BQ_);
  if (fullws){
    gemm(1,1, memory,256,0, align_wm,256,0, BK_,256,256, nullptr,0, nullptr,mn_bf,256,0, nullptr,0, nullptr,0, 1);
    l2norm_rows<<<BK_/4,256,0,stream>>>(mn_bf, BK_);
    gemm(0,0, qn_bf,256,(long)200*256, mn_bf,256,(long)K_*256, 200,K_,256,
         nullptr,0, simbuf,nullptr,K_,(long)200*K_, nullptr,0, nullptr,0, B_);
    topk_kernel<<<BQ_,256,0,stream>>>(simbuf, nullptr, K_, 96, vals96, idx96);
  } else {
    for (int b=0;b<B_;b++){
      gemm(1,1, memory + (size_t)b*K_*256,256,0, align_wm,256,0, K_,256,256,
           nullptr,0, nullptr,mn_bf,256,0, nullptr,0, nullptr,0, 1);
      l2norm_rows<<<K_/4,256,0,stream>>>(mn_bf, K_);
      for (int q0=0; q0<Q_; q0+=simRows){
        int rows = (Q_ - q0 < simRows) ? (Q_ - q0) : simRows;
        gemm(0,0, qn_bf + ((size_t)b*200+q0)*256,256,0, mn_bf,256,0, rows,K_,256,
             nullptr,0, simbuf,nullptr,K_,0, nullptr,0, nullptr,0, 1);
        topk_kernel<<<rows,256,0,stream>>>(simbuf, nullptr, K_, 96,
             vals96 + ((size_t)b*200+q0)*96, idx96 + ((size_t)b*200+q0)*96);
      }
    }
  }
  align_combine<<<BQ_,256,0,stream>>>(vals96, idx96, memory, alignedv);

  // --- gate MLP ---
  make_cat<<<BQ_,256,0,stream>>>(q, alignedv, cat_bf);
  gemm(0,1, cat_bf,512,0, gate_w1,512,0, BQ_,256,512, gate_b1,1, nullptr,h_bf,256,0, nullptr,0, nullptr,0, 1);
  gemm(0,1, h_bf,256,0, gate_w2,256,0, BQ_,256,256, gate_b2,2, gatebuf,nullptr,256,0, nullptr,0, nullptr,0, 1);
  combine_gate<<<BQ_,256,0,stream>>>(q, q_pos, alignedv, gatebuf, qx, qx_bf, qk_bf);

  // --- self attention ---
  gemm(0,1, qk_bf,256,0, sa_in_w,256,0, BQ_,512,256, sa_in_b,0, nullptr,qkv_bf,768,0, nullptr,0, nullptr,0, 1);
  gemm(0,1, qx_bf,256,0, sa_in_w+512*256,256,0, BQ_,256,256, sa_in_b+512,0, nullptr,qkv_bf+512,768,0, nullptr,0, nullptr,0, 1);
  attn_kernel<<<dim3(4,H_,B_),256,0,stream>>>(qkv_bf,768, qkv_bf,768,256,512,200,
      nullptr,nullptr, attO_bf, ascale);
  gemm(0,1, attO_bf,256,0, sa_out_w,256,0, BQ_,256,256, sa_out_b,0, q2,nullptr,256,0, nullptr,0, nullptr,0, 1);
  add_ln<<<BQ_,256,0,stream>>>(qx, q2, n1_g, n1_b, q_pos, qx, qx_bf, qpos2_bf);

  // --- cross-memory sparsify (importance = max over Q of sim2, then top-1024) ---
  gemm(0,1, qx_bf,256,0, cross_wq,256,0, BQ_,256,256, nullptr,0, nullptr,qn_bf,256,0, nullptr,0, nullptr,0, 1);
  l2norm_rows<<<BQ_/4,256,0,stream>>>(qn_bf, BQ_);
  fill_u32<<<(B_*K_+255)/256,256,0,stream>>>(imp, 0u, B_*K_);
  if (fullws){
    gemm(1,1, memory,256,0, cross_wm,256,0, BK_,256,256, nullptr,0, nullptr,mn_bf,256,0, nullptr,0, nullptr,0, 1);
    l2norm_rows<<<BK_/4,256,0,stream>>>(mn_bf, BK_);
    gemm(0,0, qn_bf,256,(long)200*256, mn_bf,256,(long)K_*256, 200,K_,256,
         nullptr,0, nullptr,nullptr,0,0, imp,(long)K_, nullptr,0, B_);
  } else {
    for (int b=0;b<B_;b++){
      gemm(1,1, memory + (size_t)b*K_*256,256,0, cross_wm,256,0, K_,256,256,
           nullptr,0, nullptr,mn_bf,256,0, nullptr,0, nullptr,0, 1);
      l2norm_rows<<<K_/4,256,0,stream>>>(mn_bf, K_);
      gemm(0,0, qn_bf + (size_t)b*200*256,256,0, mn_bf,256,0, 200,K_,256,
           nullptr,0, nullptr,nullptr,0,0, imp + (size_t)b*K_,(long)K_, nullptr,0, 1);
    }
  }
  topk_kernel<<<B_,256,0,stream>>>(nullptr, imp, K_, CROSSK_, vals96 /*scratch*/, kidx);

  // --- cross attention (kvbuf aliases mn region; mn is dead now) ---
  gemm(1,1, memory,256,(long)K_*256, ca_in_w+256*256,256,0, CROSSK_,512,256,
       ca_in_b+256,0, nullptr,kvbuf,512,(long)CROSSK_*512, nullptr,0, kidx,(long)CROSSK_, B_);
  gemm(0,1, qpos2_bf,256,0, ca_in_w,256,0, BQ_,256,256, ca_in_b,0, nullptr,cq_bf,256,0, nullptr,0, nullptr,0, 1);
  attn_kernel<<<dim3(4,H_,B_),256,0,stream>>>(cq_bf,256, kvbuf,512,0,256,CROSSK_,
      cbias, kidx, attO_bf, ascale);
  gemm(0,1, attO_bf,256,0, ca_out_w,256,0, BQ_,256,256, ca_out_b,0, q2,nullptr,256,0, nullptr,0, nullptr,0, 1);
  add_ln<<<BQ_,256,0,stream>>>(qx, q2, n2_g, n2_b, nullptr, qx, qx_bf, nullptr);

  // --- FFN + final LN -> d_out (fp32) ---
  gemm(0,1, qx_bf,256,0, ffn_w1,256,0, BQ_,FF_,256, ffn_b1,1, nullptr,f1_bf,FF_,0, nullptr,0, nullptr,0, 1);
  gemm(0,1, f1_bf,FF_,0, ffn_w2,FF_,0, BQ_,256,FF_, ffn_b2,0, f2buf,nullptr,256,0, nullptr,0, nullptr,0, 1);
  add_ln<<<BQ_,256,0,stream>>>(qx, f2buf, n3_g, n3_b, nullptr, out, nullptr, nullptr);

  (void)in_sizes; (void)n_in; (void)out_size;
}